// Round 1
// baseline (29165.829 us; speedup 1.0000x reference)
//
#include <hip/hip_runtime.h>
#include <hip/hip_bf16.h>

#define B_ 256
#define S_ 512
#define H_ 1024
#define C_ 10

typedef __attribute__((ext_vector_type(8))) short s8v;      // 8 bf16 (4 VGPRs) - MFMA A/B frag
typedef __attribute__((ext_vector_type(4))) float f4v;      // MFMA C/D frag

// ---------------- workspace layout (bytes) ----------------
// [0, 4096)                      : barrier counters (4 x uint, 1KB apart), zeroed per launch
// [4096, 4096+524288)            : xT  (S x B fp32)   = 512*256*4
// [528384, 528384+524288)        : h0  (B x H bf16)   = 256*1024*2, zeroed per launch
// [1052672, 1052672+524288)      : h1  (B x H bf16)
// [1576960, 1576960+8388608)     : Wp  (packed bf16 weights, fragment-linear)
// total ~9.5 MB

// Pack W_g[col][k] (4 matrices, each H x H fp32 row-major) into fragment-linear bf16:
// block index = ((g*64 + ct)*32 + kc), each block = 64 lanes * 16B.
// lane l of block holds B[k = kc*32 + (l>>4)*8 + j][col = ct*16 + (l&15)] = W_g[col][k]
__global__ void prep_w(const float* __restrict__ wg, const float* __restrict__ wi,
                       const float* __restrict__ wf, const float* __restrict__ wo,
                       __hip_bfloat16* __restrict__ Wp) {
    int idx = blockIdx.x * 256 + threadIdx.x;        // 4*1024*128 = 524288 groups of 8
    int g   = idx >> 17;
    int rem = idx & 131071;
    int col = rem >> 7;                              // 0..1023
    int kg  = rem & 127;                             // k0 = kg*8
    const float* src = (g == 0 ? wg : g == 1 ? wi : g == 2 ? wf : wo) + col * H_ + kg * 8;
    int kc   = kg >> 2;                              // k-chunk of 32
    int quad = kg & 3;
    int lane = quad * 16 + (col & 15);
    int ct   = col >> 4;
    int blk  = (g * 64 + ct) * 32 + kc;
    __hip_bfloat16* dst = Wp + blk * 512 + lane * 8; // block = 512 bf16 elems
#pragma unroll
    for (int j = 0; j < 8; ++j) dst[j] = __float2bfloat16(src[j]);
}

// xT[t][b] = x[b][t]
__global__ void prep_x(const float* __restrict__ x, float* __restrict__ xT) {
    int i = blockIdx.x * 256 + threadIdx.x;          // 131072
    int t = i >> 8, b = i & 255;
    xT[i] = x[b * S_ + t];
}

__device__ __forceinline__ float sigmoid_f(float x) { return 1.0f / (1.0f + __expf(-x)); }
__device__ __forceinline__ float tanh_f(float x)    { return 2.0f / (1.0f + __expf(-2.0f * x)) - 1.0f; }

__global__ __launch_bounds__(256) void lstm_main(
    const float* __restrict__ xT,
    const float* __restrict__ wgx, const float* __restrict__ wix,
    const float* __restrict__ wfx, const float* __restrict__ wox,
    const float* __restrict__ bg,  const float* __restrict__ bi,
    const float* __restrict__ bf,  const float* __restrict__ bo,
    const __hip_bfloat16* __restrict__ Wp,
    __hip_bfloat16* __restrict__ h0, __hip_bfloat16* __restrict__ h1,
    const float* __restrict__ wph, const float* __restrict__ bp,
    float* __restrict__ out,
    unsigned* __restrict__ counters)
{
    const int tid  = threadIdx.x;
    const int wgid = blockIdx.x;         // 256 blocks
    const int m    = wgid >> 6;          // batch tile 0..3 (64 rows)
    const int n    = wgid & 63;          // hidden col tile 0..63 (16 cols)
    const int w    = tid >> 6;           // wave 0..3
    const int l    = tid & 63;
    const int quad = l >> 4;
    const int l16  = l & 15;
    const int rowbase = m * 64 + w * 16; // this wave's 16 batch rows
    const int col     = n * 16 + l16;    // this lane's hidden unit

    // per-lane gate params (input weights + biases for this hidden unit)
    const float wx0 = wgx[col], wx1 = wix[col], wx2 = wfx[col], wx3 = wox[col];
    const float bb0 = bg[col],  bb1 = bi[col],  bb2 = bf[col],  bb3 = bo[col];

    // persistent cell state: rows quad*4 + r (r=0..3), column `col`
    float c0 = 0.f, c1 = 0.f, c2 = 0.f, c3 = 0.f;

    // B fragment base pointers (fragment-linear layout; advance 64 s8v per k-chunk)
    const s8v* Wv = (const s8v*)Wp;
    const s8v* pb0 = Wv + ((0 * 64 + n) * 32) * 64 + l;
    const s8v* pb1 = Wv + ((1 * 64 + n) * 32) * 64 + l;
    const s8v* pb2 = Wv + ((2 * 64 + n) * 32) * 64 + l;
    const s8v* pb3 = Wv + ((3 * 64 + n) * 32) * 64 + l;

    unsigned* ctr = counters + m * 256;  // one counter per batch-tile group, 1KB apart

    for (int t = 0; t < S_; ++t) {
        const __hip_bfloat16* hin  = (t & 1) ? h1 : h0;
        __hip_bfloat16*       hout = (t & 1) ? h0 : h1;
        // A frag: lane holds h[rowbase + l16][kc*32 + quad*8 + j]
        const s8v* pa = (const s8v*)hin + ((rowbase + l16) * 128 + quad);

        f4v acc0 = {0.f, 0.f, 0.f, 0.f}, acc1 = acc0, acc2 = acc0, acc3 = acc0;
#pragma unroll 4
        for (int kc = 0; kc < 32; ++kc) {
            s8v a = pa[kc * 4];
            acc0 = __builtin_amdgcn_mfma_f32_16x16x32_bf16(a, pb0[kc * 64], acc0, 0, 0, 0);
            acc1 = __builtin_amdgcn_mfma_f32_16x16x32_bf16(a, pb1[kc * 64], acc1, 0, 0, 0);
            acc2 = __builtin_amdgcn_mfma_f32_16x16x32_bf16(a, pb2[kc * 64], acc2, 0, 0, 0);
            acc3 = __builtin_amdgcn_mfma_f32_16x16x32_bf16(a, pb3[kc * 64], acc3, 0, 0, 0);
        }

        // epilogue: rows rowbase + quad*4 + r  (C/D layout: row = quad*4 + reg, col = l16)
        float4 xv = *(const float4*)(xT + t * B_ + rowbase + quad * 4);
        float xa[4] = {xv.x, xv.y, xv.z, xv.w};
        float cs[4] = {c0, c1, c2, c3};
#pragma unroll
        for (int r = 0; r < 4; ++r) {
            float pg = acc0[r] + xa[r] * wx0 + bb0;
            float pi = acc1[r] + xa[r] * wx1 + bb1;
            float pf = acc2[r] + xa[r] * wx2 + bb2;
            float po = acc3[r] + xa[r] * wx3 + bb3;
            float gv = tanh_f(pg);
            float iv = sigmoid_f(pi);
            float fv = sigmoid_f(pf);
            float ov = sigmoid_f(po);
            float cn = gv * iv + cs[r] * fv;
            cs[r] = cn;
            float hv = tanh_f(cn) * ov;
            int brow = rowbase + quad * 4 + r;
            hout[brow * H_ + col] = __float2bfloat16(hv);
        }
        c0 = cs[0]; c1 = cs[1]; c2 = cs[2]; c3 = cs[3];

        // group barrier (64 producers per batch-tile), monotonic counter
        __threadfence();
        __syncthreads();
        if (tid == 0) {
            __hip_atomic_fetch_add(ctr, 1u, __ATOMIC_ACQ_REL, __HIP_MEMORY_SCOPE_AGENT);
            unsigned target = (unsigned)(t + 1) * 64u;
            while (__hip_atomic_load(ctr, __ATOMIC_ACQUIRE, __HIP_MEMORY_SCOPE_AGENT) < target) {
                __builtin_amdgcn_s_sleep(2);
            }
        }
        __syncthreads();
        __threadfence();
    }

    // final projection: out[b][cc] = sum_k h_final[b][k] * wph[cc][k] + bp[cc]
    // h_final is in h0 (t=511 odd wrote h0). One wave per (b,cc) pair.
    const __hip_bfloat16* hf = h0;
    int wave_global = wgid * 4 + w;      // 0..1023
    for (int p = wave_global; p < B_ * C_; p += 1024) {
        int row = p / C_;
        int cc  = p - row * C_;
        float acc = 0.f;
        const __hip_bfloat16* hr = hf + row * H_;
        const float* wr = wph + cc * H_;
#pragma unroll
        for (int j = 0; j < 16; ++j) {
            int k = j * 64 + l;
            acc += __bfloat162float(hr[k]) * wr[k];
        }
#pragma unroll
        for (int off = 32; off > 0; off >>= 1) acc += __shfl_down(acc, off, 64);
        if (l == 0) out[p] = acc + bp[cc];
    }
}

extern "C" void kernel_launch(void* const* d_in, const int* in_sizes, int n_in,
                              void* d_out, int out_size, void* d_ws, size_t ws_size,
                              hipStream_t stream) {
    const float* x   = (const float*)d_in[0];
    const float* wgx = (const float*)d_in[1];
    const float* wix = (const float*)d_in[2];
    const float* wfx = (const float*)d_in[3];
    const float* wox = (const float*)d_in[4];
    const float* wgh = (const float*)d_in[5];
    const float* wih = (const float*)d_in[6];
    const float* wfh = (const float*)d_in[7];
    const float* woh = (const float*)d_in[8];
    const float* wph = (const float*)d_in[9];
    const float* bg  = (const float*)d_in[10];
    const float* bi  = (const float*)d_in[11];
    const float* bf  = (const float*)d_in[12];
    const float* bo  = (const float*)d_in[13];
    const float* bp  = (const float*)d_in[14];
    float* out = (float*)d_out;

    char* ws = (char*)d_ws;
    unsigned*       counters = (unsigned*)ws;
    float*          xT = (float*)(ws + 4096);
    __hip_bfloat16* h0 = (__hip_bfloat16*)(ws + 4096 + 524288);
    __hip_bfloat16* h1 = (__hip_bfloat16*)(ws + 4096 + 2 * 524288);
    __hip_bfloat16* Wp = (__hip_bfloat16*)(ws + 4096 + 3 * 524288);

    hipMemsetAsync(counters, 0, 4096, stream);            // barrier counters = 0
    hipMemsetAsync(h0, 0, 524288, stream);                // h_0 = 0 (bf16 zeros)
    prep_x<<<512, 256, 0, stream>>>(x, xT);
    prep_w<<<2048, 256, 0, stream>>>(wgh, wih, wfh, woh, Wp);
    lstm_main<<<256, 256, 0, stream>>>(xT, wgx, wix, wfx, wox, bg, bi, bf, bo,
                                       Wp, h0, h1, wph, bp, out, counters);
}

// Round 2
// 10681.905 us; speedup vs baseline: 2.7304x; 2.7304x over previous
//
#include <hip/hip_runtime.h>
#include <hip/hip_bf16.h>

#define B_ 256
#define S_ 512
#define H_ 1024
#define C_ 10

typedef unsigned long long u64;
typedef __attribute__((ext_vector_type(8))) short s8v;      // 8 bf16 (4 VGPRs) - MFMA A/B frag
typedef __attribute__((ext_vector_type(4))) float f4v;      // MFMA C/D frag

// ---------------- workspace layout (bytes) ----------------
// [0, 4096)                      : flags[4 groups][64 blocks] (uint), zeroed per launch
// [4096, +524288)                : xT  (S x B fp32)
// [528384, +524288)              : h0  (B x H bf16), zeroed per launch
// [1052672, +524288)             : h1  (B x H bf16)
// [1576960, +8388608)            : Wp  (packed bf16 weights, fragment-linear, MFMA A operand)

// Pack W_g[out][k] (4 matrices, H x H fp32 row-major) into A-fragment-linear bf16:
// block index = ((g*64 + ot)*32 + kc), each block = 64 lanes * 16B.
// lane l = quad*16 + (out&15) holds W_g[out = ot*16 + (out&15)][k = kc*32 + quad*8 + j]
__global__ void prep_w(const float* __restrict__ wg, const float* __restrict__ wi,
                       const float* __restrict__ wf, const float* __restrict__ wo,
                       __hip_bfloat16* __restrict__ Wp) {
    int idx = blockIdx.x * 256 + threadIdx.x;        // 4*1024*128 = 524288 groups of 8
    int g   = idx >> 17;
    int rem = idx & 131071;
    int o   = rem >> 7;                              // out col 0..1023
    int kg  = rem & 127;                             // k0 = kg*8
    const float* src = (g == 0 ? wg : g == 1 ? wi : g == 2 ? wf : wo) + o * H_ + kg * 8;
    int kc   = kg >> 2;
    int quad = kg & 3;
    int lane = quad * 16 + (o & 15);
    int ot   = o >> 4;
    int blk  = (g * 64 + ot) * 32 + kc;
    __hip_bfloat16* dst = Wp + blk * 512 + lane * 8;
#pragma unroll
    for (int j = 0; j < 8; ++j) dst[j] = __float2bfloat16(src[j]);
}

// xT[t][b] = x[b][t]
__global__ void prep_x(const float* __restrict__ x, float* __restrict__ xT) {
    int i = blockIdx.x * 256 + threadIdx.x;          // 131072
    int t = i >> 8, b = i & 255;
    xT[i] = x[b * S_ + t];
}

__device__ __forceinline__ float sigmoid_f(float x) { return 1.0f / (1.0f + __expf(-x)); }
__device__ __forceinline__ float tanh_f(float x)    { return 2.0f / (1.0f + __expf(-2.0f * x)) - 1.0f; }

__device__ __forceinline__ float bf2f(unsigned short u) {
    union { unsigned i; float f; } x; x.i = ((unsigned)u) << 16; return x.f;
}
__device__ __forceinline__ unsigned short f2bf(float f) {
    union { __hip_bfloat16 h; unsigned short s; } x; x.h = __float2bfloat16(f); return x.s;
}

// wave-level group barrier: all 64 flags of group >= tgt. One coalesced sc1 load + ballot.
__device__ __forceinline__ void group_wait(const unsigned* fl, int l, unsigned tgt) {
    for (;;) {
        unsigned v = __hip_atomic_load(fl + l, __ATOMIC_RELAXED, __HIP_MEMORY_SCOPE_AGENT);
        if (__ballot(v < tgt) == 0ull) break;
        __builtin_amdgcn_s_sleep(1);
    }
}

__global__ __launch_bounds__(256, 1) void lstm_main(
    const float* __restrict__ xT,
    const float* __restrict__ wgx, const float* __restrict__ wix,
    const float* __restrict__ wfx, const float* __restrict__ wox,
    const float* __restrict__ bg,  const float* __restrict__ bi,
    const float* __restrict__ bf,  const float* __restrict__ bo,
    const __hip_bfloat16* __restrict__ Wp,
    __hip_bfloat16* __restrict__ h0, __hip_bfloat16* __restrict__ h1,
    const float* __restrict__ wph, const float* __restrict__ bp,
    float* __restrict__ out,
    unsigned* __restrict__ flags)
{
    const int tid  = threadIdx.x;
    const int wgid = blockIdx.x;         // 256 blocks
    const int m    = wgid >> 6;          // batch group 0..3 (64 rows)
    const int n    = wgid & 63;          // out-tile 0..63 (16 hidden cols per gate)
    const int w    = tid >> 6;           // wave 0..3 (batch sub-tile)
    const int l    = tid & 63;
    const int quad = l >> 4;
    const int l16  = l & 15;
    const int b    = m * 64 + w * 16 + l16;  // this lane's batch row (B-frag n + D col)
    const int out0 = n * 16 + quad * 4;      // first of this lane's 4 hidden cols (D rows)

    // per-lane gate params for the 4 consecutive hidden cols
    float wxg[4], wxi[4], wxf[4], wxo[4], bbg[4], bbi[4], bbf[4], bbo[4];
    *(float4*)wxg = *(const float4*)(wgx + out0);
    *(float4*)wxi = *(const float4*)(wix + out0);
    *(float4*)wxf = *(const float4*)(wfx + out0);
    *(float4*)wxo = *(const float4*)(wox + out0);
    *(float4*)bbg = *(const float4*)(bg + out0);
    *(float4*)bbi = *(const float4*)(bi + out0);
    *(float4*)bbf = *(const float4*)(bf + out0);
    *(float4*)bbo = *(const float4*)(bo + out0);

    float cs[4] = {0.f, 0.f, 0.f, 0.f};     // persistent cell state

    // W A-fragment base pointers (stationary operand, normal cached loads)
    const s8v* Wv  = (const s8v*)Wp;
    const s8v* pw0 = Wv + ((0 * 64 + n) * 32) * 64 + l;
    const s8v* pw1 = Wv + ((1 * 64 + n) * 32) * 64 + l;
    const s8v* pw2 = Wv + ((2 * 64 + n) * 32) * 64 + l;
    const s8v* pw3 = Wv + ((3 * 64 + n) * 32) * 64 + l;

    const unsigned* fl = flags + m * 64;
    unsigned* myflag   = flags + m * 64 + n;

    for (int t = 0; t < S_; ++t) {
        const __hip_bfloat16* hin  = (t & 1) ? h1 : h0;
        __hip_bfloat16*       hout = (t & 1) ? h0 : h1;

        group_wait(fl, l, (unsigned)t);      // h(t) ready in LLC (t=0 trivially passes)

        // preload all h B-fragments: lane holds h[b][kc*32 + quad*8 + j], via sc1 (LLC) loads
        const u64* hb = (const u64*)hin + (size_t)b * 256 + quad * 2;
        u64 hq[64];
#pragma unroll
        for (int kc = 0; kc < 32; ++kc) {
            hq[2 * kc]     = __hip_atomic_load(hb + kc * 8,     __ATOMIC_RELAXED, __HIP_MEMORY_SCOPE_AGENT);
            hq[2 * kc + 1] = __hip_atomic_load(hb + kc * 8 + 1, __ATOMIC_RELAXED, __HIP_MEMORY_SCOPE_AGENT);
        }

        f4v acc0 = {0.f, 0.f, 0.f, 0.f}, acc1 = acc0, acc2 = acc0, acc3 = acc0;
#pragma unroll
        for (int kc = 0; kc < 32; ++kc) {
            union { u64 q[2]; s8v v; } hf_;
            hf_.q[0] = hq[2 * kc]; hf_.q[1] = hq[2 * kc + 1];
            s8v hv = hf_.v;
            acc0 = __builtin_amdgcn_mfma_f32_16x16x32_bf16(pw0[kc * 64], hv, acc0, 0, 0, 0);
            acc1 = __builtin_amdgcn_mfma_f32_16x16x32_bf16(pw1[kc * 64], hv, acc1, 0, 0, 0);
            acc2 = __builtin_amdgcn_mfma_f32_16x16x32_bf16(pw2[kc * 64], hv, acc2, 0, 0, 0);
            acc3 = __builtin_amdgcn_mfma_f32_16x16x32_bf16(pw3[kc * 64], hv, acc3, 0, 0, 0);
        }

        // epilogue: D row (quad*4+r) = hidden col out0+r, D col (l16) = batch b
        float xa = xT[t * B_ + b];
        unsigned short hs[4];
#pragma unroll
        for (int r = 0; r < 4; ++r) {
            float pg = acc0[r] + xa * wxg[r] + bbg[r];
            float pi = acc1[r] + xa * wxi[r] + bbi[r];
            float pf = acc2[r] + xa * wxf[r] + bbf[r];
            float po = acc3[r] + xa * wxo[r] + bbo[r];
            float gv = tanh_f(pg);
            float iv = sigmoid_f(pi);
            float fv = sigmoid_f(pf);
            float ov = sigmoid_f(po);
            float cn = gv * iv + cs[r] * fv;
            cs[r] = cn;
            hs[r] = f2bf(tanh_f(cn) * ov);
        }
        union { unsigned short s[4]; u64 q; } hp_;
        hp_.s[0] = hs[0]; hp_.s[1] = hs[1]; hp_.s[2] = hs[2]; hp_.s[3] = hs[3];
        // one 8B sc1 store: h[b][out0 .. out0+3]
        __hip_atomic_store((u64*)(hout + b * H_ + out0), hp_.q,
                           __ATOMIC_RELAXED, __HIP_MEMORY_SCOPE_AGENT);

        __syncthreads();                     // drains vmcnt(0): h stores are at LLC
        if (tid == 0)
            __hip_atomic_store(myflag, (unsigned)(t + 1), __ATOMIC_RELAXED, __HIP_MEMORY_SCOPE_AGENT);
    }

    group_wait(fl, l, (unsigned)S_);         // final h (in h0) visible

    // projection restricted to own group's rows: out[row][cc], rows [64m, 64m+64)
    const __hip_bfloat16* hf = h0;           // t=511 (odd) wrote h0
    int wig = n * 4 + w;                     // wave index in group, 0..255
    for (int p = wig; p < 64 * C_; p += 256) {
        int row = m * 64 + p / C_;
        int cc  = p % C_;
        const u64* hr = (const u64*)(hf + row * H_);
        const float* wr = wph + cc * H_;
        float acc = 0.f;
#pragma unroll
        for (int j = 0; j < 4; ++j) {
            int k = j * 256 + l * 4;
            u64 hv4 = __hip_atomic_load(hr + (k >> 2), __ATOMIC_RELAXED, __HIP_MEMORY_SCOPE_AGENT);
            union { u64 q; unsigned short s[4]; } u_; u_.q = hv4;
            float4 wv = *(const float4*)(wr + k);
            acc += bf2f(u_.s[0]) * wv.x + bf2f(u_.s[1]) * wv.y
                 + bf2f(u_.s[2]) * wv.z + bf2f(u_.s[3]) * wv.w;
        }
#pragma unroll
        for (int off = 32; off > 0; off >>= 1) acc += __shfl_down(acc, off, 64);
        if (l == 0) out[row * C_ + cc] = acc + bp[cc];
    }
}

extern "C" void kernel_launch(void* const* d_in, const int* in_sizes, int n_in,
                              void* d_out, int out_size, void* d_ws, size_t ws_size,
                              hipStream_t stream) {
    const float* x   = (const float*)d_in[0];
    const float* wgx = (const float*)d_in[1];
    const float* wix = (const float*)d_in[2];
    const float* wfx = (const float*)d_in[3];
    const float* wox = (const float*)d_in[4];
    const float* wgh = (const float*)d_in[5];
    const float* wih = (const float*)d_in[6];
    const float* wfh = (const float*)d_in[7];
    const float* woh = (const float*)d_in[8];
    const float* wph = (const float*)d_in[9];
    const float* bg  = (const float*)d_in[10];
    const float* bi  = (const float*)d_in[11];
    const float* bf  = (const float*)d_in[12];
    const float* bo  = (const float*)d_in[13];
    const float* bp  = (const float*)d_in[14];
    float* out = (float*)d_out;

    char* ws = (char*)d_ws;
    unsigned*       flags = (unsigned*)ws;
    float*          xT = (float*)(ws + 4096);
    __hip_bfloat16* h0 = (__hip_bfloat16*)(ws + 4096 + 524288);
    __hip_bfloat16* h1 = (__hip_bfloat16*)(ws + 4096 + 2 * 524288);
    __hip_bfloat16* Wp = (__hip_bfloat16*)(ws + 4096 + 3 * 524288);

    hipMemsetAsync(flags, 0, 4096, stream);               // flag barrier = 0
    hipMemsetAsync(h0, 0, 524288, stream);                // h_0 = 0
    prep_x<<<512, 256, 0, stream>>>(x, xT);
    prep_w<<<2048, 256, 0, stream>>>(wgh, wih, wfh, woh, Wp);
    lstm_main<<<256, 256, 0, stream>>>(xT, wgx, wix, wfx, wox, bg, bi, bf, bo,
                                       Wp, h0, h1, wph, bp, out, flags);
}

// Round 3
// 6843.913 us; speedup vs baseline: 4.2616x; 1.5608x over previous
//
#include <hip/hip_runtime.h>
#include <hip/hip_bf16.h>

#define B_ 256
#define S_ 512
#define H_ 1024
#define C_ 10

typedef unsigned long long u64;
typedef __attribute__((ext_vector_type(8))) short s8v;      // 8 bf16 (4 VGPRs) - MFMA A/B frag
typedef __attribute__((ext_vector_type(4))) float f4v;      // MFMA C/D frag

// ---------------- workspace layout (bytes) ----------------
// [0, 4096)                      : flags[4 groups][64 blocks] (uint), zeroed per launch
// [4096, +524288)                : xT  (S x B fp32)
// [528384, +524288)              : h0  (B x H bf16), zeroed per launch
// [1052672, +524288)             : h1  (B x H bf16)
// [1576960, +8388608)            : Wp  (packed bf16 weights, fragment-linear, MFMA A operand)

// Pack W_g[out][k] (4 matrices, H x H fp32 row-major) into A-fragment-linear bf16:
// block index = ((g*64 + ot)*32 + kc), each block = 64 lanes * 16B.
// lane l = quad*16 + (out&15) holds W_g[out = ot*16 + (out&15)][k = kc*32 + quad*8 + j]
__global__ void prep_w(const float* __restrict__ wg, const float* __restrict__ wi,
                       const float* __restrict__ wf, const float* __restrict__ wo,
                       __hip_bfloat16* __restrict__ Wp) {
    int idx = blockIdx.x * 256 + threadIdx.x;        // 4*1024*128 = 524288 groups of 8
    int g   = idx >> 17;
    int rem = idx & 131071;
    int o   = rem >> 7;                              // out col 0..1023
    int kg  = rem & 127;                             // k0 = kg*8
    const float* src = (g == 0 ? wg : g == 1 ? wi : g == 2 ? wf : wo) + o * H_ + kg * 8;
    int kc   = kg >> 2;
    int quad = kg & 3;
    int lane = quad * 16 + (o & 15);
    int ot   = o >> 4;
    int blk  = (g * 64 + ot) * 32 + kc;
    __hip_bfloat16* dst = Wp + blk * 512 + lane * 8;
#pragma unroll
    for (int j = 0; j < 8; ++j) dst[j] = __float2bfloat16(src[j]);
}

// xT[t][b] = x[b][t]
__global__ void prep_x(const float* __restrict__ x, float* __restrict__ xT) {
    int i = blockIdx.x * 256 + threadIdx.x;          // 131072
    int t = i >> 8, b = i & 255;
    xT[i] = x[b * S_ + t];
}

__device__ __forceinline__ float sigmoid_f(float x) { return 1.0f / (1.0f + __expf(-x)); }
__device__ __forceinline__ float tanh_f(float x)    { return 2.0f / (1.0f + __expf(-2.0f * x)) - 1.0f; }

__device__ __forceinline__ float bf2f(unsigned short u) {
    union { unsigned i; float f; } x; x.i = ((unsigned)u) << 16; return x.f;
}
__device__ __forceinline__ unsigned short f2bf(float f) {
    union { __hip_bfloat16 h; unsigned short s; } x; x.h = __float2bfloat16(f); return x.s;
}

// wave-level group barrier: all 64 flags of group >= tgt. One coalesced load + ballot.
__device__ __forceinline__ void group_wait(const unsigned* fl, int l, unsigned tgt) {
    for (;;) {
        unsigned v = __hip_atomic_load(fl + l, __ATOMIC_RELAXED, __HIP_MEMORY_SCOPE_AGENT);
        if (__ballot(v < tgt) == 0ull) break;
        __builtin_amdgcn_s_sleep(1);
    }
}

__global__ __launch_bounds__(256, 1) void lstm_main(
    const float* __restrict__ xT,
    const float* __restrict__ wgx, const float* __restrict__ wix,
    const float* __restrict__ wfx, const float* __restrict__ wox,
    const float* __restrict__ bg,  const float* __restrict__ bi,
    const float* __restrict__ bf,  const float* __restrict__ bo,
    const __hip_bfloat16* __restrict__ Wp,
    __hip_bfloat16* __restrict__ h0, __hip_bfloat16* __restrict__ h1,
    const float* __restrict__ wph, const float* __restrict__ bp,
    float* __restrict__ out,
    unsigned* __restrict__ flags)
{
    // weights LDS-stationary: 4 gates x 32 kc x 64 lanes x 16B = 128 KB
    __shared__ s8v Wlds[4 * 32 * 64];

    const int tid  = threadIdx.x;
    const int wgid = blockIdx.x;         // 256 blocks
    const int m    = wgid >> 6;          // batch group 0..3 (64 rows)
    const int n    = wgid & 63;          // out-tile 0..63 (16 hidden cols per gate)
    const int w    = tid >> 6;           // wave 0..3 (batch sub-tile)
    const int l    = tid & 63;
    const int quad = l >> 4;
    const int l16  = l & 15;
    const int b    = m * 64 + w * 16 + l16;  // this lane's batch row (B-frag col / D col)
    const int out0 = n * 16 + quad * 4;      // first of this lane's 4 hidden cols (D rows)

    // one-time: stage this block's weights into LDS (coalesced 16B loads, cached path)
    {
        const s8v* Wv = (const s8v*)Wp;
#pragma unroll
        for (int j = 0; j < 32; ++j) {
            int idx = j * 256 + tid;             // 0..8191
            int g   = idx >> 11;
            int rem = idx & 2047;                // kc*64 + lane
            Wlds[g * 2048 + rem] = Wv[((g * 64 + n) * 32) * 64 + rem];
        }
    }

    // per-lane gate params for the 4 consecutive hidden cols
    float wxg[4], wxi[4], wxf[4], wxo[4], bbg[4], bbi[4], bbf[4], bbo[4];
    *(float4*)wxg = *(const float4*)(wgx + out0);
    *(float4*)wxi = *(const float4*)(wix + out0);
    *(float4*)wxf = *(const float4*)(wfx + out0);
    *(float4*)wxo = *(const float4*)(wox + out0);
    *(float4*)bbg = *(const float4*)(bg + out0);
    *(float4*)bbi = *(const float4*)(bi + out0);
    *(float4*)bbf = *(const float4*)(bf + out0);
    *(float4*)bbo = *(const float4*)(bo + out0);

    float cs[4] = {0.f, 0.f, 0.f, 0.f};     // persistent cell state

    const unsigned* fl = flags + m * 64;
    unsigned* myflag   = flags + m * 64 + n;

    __syncthreads();                         // LDS weights ready

    for (int t = 0; t < S_; ++t) {
        const __hip_bfloat16* hin  = (t & 1) ? h1 : h0;
        __hip_bfloat16*       hout = (t & 1) ? h0 : h1;

        group_wait(fl, l, (unsigned)t);      // h(t) ready at coherence point

        // preload all h B-fragments: lane holds h[b][kc*32 + quad*8 + j], LLC-scope loads
        const u64* hb = (const u64*)hin + (size_t)b * 256 + quad * 2;
        u64 hq[64];
#pragma unroll
        for (int kc = 0; kc < 32; ++kc) {
            hq[2 * kc]     = __hip_atomic_load(hb + kc * 8,     __ATOMIC_RELAXED, __HIP_MEMORY_SCOPE_AGENT);
            hq[2 * kc + 1] = __hip_atomic_load(hb + kc * 8 + 1, __ATOMIC_RELAXED, __HIP_MEMORY_SCOPE_AGENT);
        }

        f4v acc0 = {0.f, 0.f, 0.f, 0.f}, acc1 = acc0, acc2 = acc0, acc3 = acc0;
#pragma unroll
        for (int kc = 0; kc < 32; ++kc) {
            union { u64 q[2]; s8v v; } hf_;
            hf_.q[0] = hq[2 * kc]; hf_.q[1] = hq[2 * kc + 1];
            s8v hv = hf_.v;
            acc0 = __builtin_amdgcn_mfma_f32_16x16x32_bf16(Wlds[0 * 2048 + kc * 64 + l], hv, acc0, 0, 0, 0);
            acc1 = __builtin_amdgcn_mfma_f32_16x16x32_bf16(Wlds[1 * 2048 + kc * 64 + l], hv, acc1, 0, 0, 0);
            acc2 = __builtin_amdgcn_mfma_f32_16x16x32_bf16(Wlds[2 * 2048 + kc * 64 + l], hv, acc2, 0, 0, 0);
            acc3 = __builtin_amdgcn_mfma_f32_16x16x32_bf16(Wlds[3 * 2048 + kc * 64 + l], hv, acc3, 0, 0, 0);
        }

        // epilogue: D row (quad*4+r) = hidden col out0+r, D col (l16) = batch b
        float xa = xT[t * B_ + b];
        unsigned short hs[4];
#pragma unroll
        for (int r = 0; r < 4; ++r) {
            float pg = acc0[r] + xa * wxg[r] + bbg[r];
            float pi = acc1[r] + xa * wxi[r] + bbi[r];
            float pf = acc2[r] + xa * wxf[r] + bbf[r];
            float po = acc3[r] + xa * wxo[r] + bbo[r];
            float gv = tanh_f(pg);
            float iv = sigmoid_f(pi);
            float fv = sigmoid_f(pf);
            float ov = sigmoid_f(po);
            float cn = gv * iv + cs[r] * fv;
            cs[r] = cn;
            hs[r] = f2bf(tanh_f(cn) * ov);
        }
        union { unsigned short s[4]; u64 q; } hp_;
        hp_.s[0] = hs[0]; hp_.s[1] = hs[1]; hp_.s[2] = hs[2]; hp_.s[3] = hs[3];
        // one 8B LLC store: h[b][out0 .. out0+3]
        __hip_atomic_store((u64*)(hout + b * H_ + out0), hp_.q,
                           __ATOMIC_RELAXED, __HIP_MEMORY_SCOPE_AGENT);

        __syncthreads();                     // drains vmcnt(0): h stores are at LLC
        if (tid == 0)
            __hip_atomic_store(myflag, (unsigned)(t + 1), __ATOMIC_RELAXED, __HIP_MEMORY_SCOPE_AGENT);
    }

    group_wait(fl, l, (unsigned)S_);         // final h (in h0) visible

    // projection restricted to own group's rows: out[row][cc], rows [64m, 64m+64)
    const __hip_bfloat16* hf = h0;           // t=511 (odd) wrote h0
    int wig = n * 4 + w;                     // wave index in group, 0..255
    for (int p = wig; p < 64 * C_; p += 256) {
        int row = m * 64 + p / C_;
        int cc  = p % C_;
        const u64* hr = (const u64*)(hf + row * H_);
        const float* wr = wph + cc * H_;
        float acc = 0.f;
#pragma unroll
        for (int j = 0; j < 4; ++j) {
            int k = j * 256 + l * 4;
            u64 hv4 = __hip_atomic_load(hr + (k >> 2), __ATOMIC_RELAXED, __HIP_MEMORY_SCOPE_AGENT);
            union { u64 q; unsigned short s[4]; } u_; u_.q = hv4;
            float4 wv = *(const float4*)(wr + k);
            acc += bf2f(u_.s[0]) * wv.x + bf2f(u_.s[1]) * wv.y
                 + bf2f(u_.s[2]) * wv.z + bf2f(u_.s[3]) * wv.w;
        }
#pragma unroll
        for (int off = 32; off > 0; off >>= 1) acc += __shfl_down(acc, off, 64);
        if (l == 0) out[row * C_ + cc] = acc + bp[cc];
    }
}

extern "C" void kernel_launch(void* const* d_in, const int* in_sizes, int n_in,
                              void* d_out, int out_size, void* d_ws, size_t ws_size,
                              hipStream_t stream) {
    const float* x   = (const float*)d_in[0];
    const float* wgx = (const float*)d_in[1];
    const float* wix = (const float*)d_in[2];
    const float* wfx = (const float*)d_in[3];
    const float* wox = (const float*)d_in[4];
    const float* wgh = (const float*)d_in[5];
    const float* wih = (const float*)d_in[6];
    const float* wfh = (const float*)d_in[7];
    const float* woh = (const float*)d_in[8];
    const float* wph = (const float*)d_in[9];
    const float* bg  = (const float*)d_in[10];
    const float* bi  = (const float*)d_in[11];
    const float* bf  = (const float*)d_in[12];
    const float* bo  = (const float*)d_in[13];
    const float* bp  = (const float*)d_in[14];
    float* out = (float*)d_out;

    char* ws = (char*)d_ws;
    unsigned*       flags = (unsigned*)ws;
    float*          xT = (float*)(ws + 4096);
    __hip_bfloat16* h0 = (__hip_bfloat16*)(ws + 4096 + 524288);
    __hip_bfloat16* h1 = (__hip_bfloat16*)(ws + 4096 + 2 * 524288);
    __hip_bfloat16* Wp = (__hip_bfloat16*)(ws + 4096 + 3 * 524288);

    hipMemsetAsync(flags, 0, 4096, stream);               // flag barrier = 0
    hipMemsetAsync(h0, 0, 524288, stream);                // h_0 = 0
    prep_x<<<512, 256, 0, stream>>>(x, xT);
    prep_w<<<2048, 256, 0, stream>>>(wgh, wih, wfh, woh, Wp);
    lstm_main<<<256, 256, 0, stream>>>(xT, wgx, wix, wfx, wox, bg, bi, bf, bo,
                                       Wp, h0, h1, wph, bp, out, flags);
}

// Round 4
// 5107.684 us; speedup vs baseline: 5.7102x; 1.3399x over previous
//
#include <hip/hip_runtime.h>
#include <hip/hip_bf16.h>

#define B_ 256
#define S_ 512
#define H_ 1024
#define C_ 10

typedef unsigned long long u64;
typedef __attribute__((ext_vector_type(8))) short s8v;      // 8 bf16 (4 VGPRs) - MFMA A/B frag
typedef __attribute__((ext_vector_type(4))) float f4v;      // MFMA C/D frag

// ---------------- workspace layout (bytes) ----------------
// [0, 4096)                      : flags[4 groups][64 blocks] (uint), zeroed per launch
// [4096, +524288)                : xT  (S x B fp32)
// [528384, +524288)              : h0  (B x H bf16), zeroed per launch
// [1052672, +524288)             : h1  (B x H bf16)
// [1576960, +8388608)            : Wp  (packed bf16 weights, fragment-linear, MFMA A operand)

// Pack W_g[out][k] (4 matrices, H x H fp32 row-major) into A-fragment-linear bf16:
// block index = ((g*64 + ot)*32 + kc), each block = 64 lanes * 16B.
// lane l = quad*16 + (out&15) holds W_g[out = ot*16 + (out&15)][k = kc*32 + quad*8 + j]
__global__ void prep_w(const float* __restrict__ wg, const float* __restrict__ wi,
                       const float* __restrict__ wf, const float* __restrict__ wo,
                       __hip_bfloat16* __restrict__ Wp) {
    int idx = blockIdx.x * 256 + threadIdx.x;        // 4*1024*128 = 524288 groups of 8
    int g   = idx >> 17;
    int rem = idx & 131071;
    int o   = rem >> 7;                              // out col 0..1023
    int kg  = rem & 127;                             // k0 = kg*8
    const float* src = (g == 0 ? wg : g == 1 ? wi : g == 2 ? wf : wo) + o * H_ + kg * 8;
    int kc   = kg >> 2;
    int quad = kg & 3;
    int lane = quad * 16 + (o & 15);
    int ot   = o >> 4;
    int blk  = (g * 64 + ot) * 32 + kc;
    __hip_bfloat16* dst = Wp + blk * 512 + lane * 8;
#pragma unroll
    for (int j = 0; j < 8; ++j) dst[j] = __float2bfloat16(src[j]);
}

// xT[t][b] = x[b][t]
__global__ void prep_x(const float* __restrict__ x, float* __restrict__ xT) {
    int i = blockIdx.x * 256 + threadIdx.x;          // 131072
    int t = i >> 8, b = i & 255;
    xT[i] = x[b * S_ + t];
}

__device__ __forceinline__ float sigmoid_f(float x) { return 1.0f / (1.0f + __expf(-x)); }
__device__ __forceinline__ float tanh_f(float x)    { return 2.0f / (1.0f + __expf(-2.0f * x)) - 1.0f; }

__device__ __forceinline__ float bf2f(unsigned short u) {
    union { unsigned i; float f; } x; x.i = ((unsigned)u) << 16; return x.f;
}
__device__ __forceinline__ unsigned short f2bf(float f) {
    union { __hip_bfloat16 h; unsigned short s; } x; x.h = __float2bfloat16(f); return x.s;
}

// wave-level group barrier: all 64 flags of group >= tgt. One coalesced load + ballot.
__device__ __forceinline__ void group_wait(const unsigned* fl, int l, unsigned tgt) {
    for (;;) {
        unsigned v = __hip_atomic_load(fl + l, __ATOMIC_RELAXED, __HIP_MEMORY_SCOPE_AGENT);
        if (__ballot(v < tgt) == 0ull) break;
        __builtin_amdgcn_s_sleep(4);
    }
}

__global__ __launch_bounds__(256, 1) void lstm_main(
    const float* __restrict__ xT,
    const float* __restrict__ wgx, const float* __restrict__ wix,
    const float* __restrict__ wfx, const float* __restrict__ wox,
    const float* __restrict__ bg,  const float* __restrict__ bi,
    const float* __restrict__ bf,  const float* __restrict__ bo,
    const __hip_bfloat16* __restrict__ Wp,
    __hip_bfloat16* __restrict__ h0, __hip_bfloat16* __restrict__ h1,
    const float* __restrict__ wph, const float* __restrict__ bp,
    float* __restrict__ out,
    unsigned* __restrict__ flags)
{
    // weights LDS-stationary: 4 gates x 32 kc x 64 lanes x 16B = 128 KB
    __shared__ s8v Wlds[4 * 32 * 64];

    const int tid  = threadIdx.x;
    const int wgid = blockIdx.x;         // 256 blocks
    const int m    = wgid >> 6;          // batch group 0..3 (64 rows)
    const int n    = wgid & 63;          // out-tile 0..63 (16 hidden cols per gate)
    const int w    = tid >> 6;           // wave 0..3 (batch sub-tile)
    const int l    = tid & 63;
    const int quad = l >> 4;
    const int l16  = l & 15;
    const int b    = m * 64 + w * 16 + l16;  // this lane's batch row (B-frag col / D col)
    const int out0 = n * 16 + quad * 4;      // first of this lane's 4 hidden cols (D rows)

    // one-time: stage this block's weights into LDS (coalesced 16B loads, cached path)
    {
        const s8v* Wv = (const s8v*)Wp;
#pragma unroll
        for (int j = 0; j < 32; ++j) {
            int idx = j * 256 + tid;             // 0..8191
            int g   = idx >> 11;
            int rem = idx & 2047;                // kc*64 + lane
            Wlds[g * 2048 + rem] = Wv[((g * 64 + n) * 32) * 64 + rem];
        }
    }

    // per-lane gate params for the 4 consecutive hidden cols
    float wxg[4], wxi[4], wxf[4], wxo[4], bbg[4], bbi[4], bbf[4], bbo[4];
    *(float4*)wxg = *(const float4*)(wgx + out0);
    *(float4*)wxi = *(const float4*)(wix + out0);
    *(float4*)wxf = *(const float4*)(wfx + out0);
    *(float4*)wxo = *(const float4*)(wox + out0);
    *(float4*)bbg = *(const float4*)(bg + out0);
    *(float4*)bbi = *(const float4*)(bi + out0);
    *(float4*)bbf = *(const float4*)(bf + out0);
    *(float4*)bbo = *(const float4*)(bo + out0);

    float cs[4] = {0.f, 0.f, 0.f, 0.f};     // persistent cell state

    const unsigned* fl = flags + m * 64;
    unsigned* myflag   = flags + m * 64 + n;

    __syncthreads();                         // LDS weights ready

    for (int t = 0; t < S_; ++t) {
        const __hip_bfloat16* hin  = (t & 1) ? h1 : h0;
        __hip_bfloat16*       hout = (t & 1) ? h0 : h1;

        // xT depends only on t — issue before the barrier wait
        float xa = xT[t * B_ + b];

        // wave 0 polls; acquire fence invalidates L1 + XCD L2 (clean, no writeback);
        // barrier releases the other waves
        if (w == 0) {
            group_wait(fl, l, (unsigned)t);
            __builtin_amdgcn_fence(__ATOMIC_ACQUIRE, "agent");
        }
        __syncthreads();

        // h B-fragments via NORMAL CACHED loads: L2 broadcasts the group slab
        // to the 8 blocks of this group on each XCD (sc1 stores kept L2 clean).
        const s8v* hb = (const s8v*)(hin + (size_t)b * H_) + quad;
        s8v hfrag[32];
#pragma unroll
        for (int kc = 0; kc < 32; ++kc) hfrag[kc] = hb[kc * 4];

        f4v acc0 = {0.f, 0.f, 0.f, 0.f}, acc1 = acc0, acc2 = acc0, acc3 = acc0;
#pragma unroll
        for (int kc = 0; kc < 32; ++kc) {
            s8v hv = hfrag[kc];
            acc0 = __builtin_amdgcn_mfma_f32_16x16x32_bf16(Wlds[0 * 2048 + kc * 64 + l], hv, acc0, 0, 0, 0);
            acc1 = __builtin_amdgcn_mfma_f32_16x16x32_bf16(Wlds[1 * 2048 + kc * 64 + l], hv, acc1, 0, 0, 0);
            acc2 = __builtin_amdgcn_mfma_f32_16x16x32_bf16(Wlds[2 * 2048 + kc * 64 + l], hv, acc2, 0, 0, 0);
            acc3 = __builtin_amdgcn_mfma_f32_16x16x32_bf16(Wlds[3 * 2048 + kc * 64 + l], hv, acc3, 0, 0, 0);
        }

        // epilogue: D row (quad*4+r) = hidden col out0+r, D col (l16) = batch b
        unsigned short hs[4];
#pragma unroll
        for (int r = 0; r < 4; ++r) {
            float pg = acc0[r] + xa * wxg[r] + bbg[r];
            float pi = acc1[r] + xa * wxi[r] + bbi[r];
            float pf = acc2[r] + xa * wxf[r] + bbf[r];
            float po = acc3[r] + xa * wxo[r] + bbo[r];
            float gv = tanh_f(pg);
            float iv = sigmoid_f(pi);
            float fv = sigmoid_f(pf);
            float ov = sigmoid_f(po);
            float cn = gv * iv + cs[r] * fv;
            cs[r] = cn;
            hs[r] = f2bf(tanh_f(cn) * ov);
        }
        union { unsigned short s[4]; u64 q; } hp_;
        hp_.s[0] = hs[0]; hp_.s[1] = hs[1]; hp_.s[2] = hs[2]; hp_.s[3] = hs[3];
        // one 8B write-through (LLC) store: h[b][out0 .. out0+3]; keeps L2 clean
        __hip_atomic_store((u64*)(hout + b * H_ + out0), hp_.q,
                           __ATOMIC_RELAXED, __HIP_MEMORY_SCOPE_AGENT);

        __syncthreads();                     // drains vmcnt(0): h stores are at LLC
        if (tid == 0)
            __hip_atomic_store(myflag, (unsigned)(t + 1), __ATOMIC_RELAXED, __HIP_MEMORY_SCOPE_AGENT);
    }

    group_wait(fl, l, (unsigned)S_);         // final h (in h0) visible

    // projection restricted to own group's rows: out[row][cc], rows [64m, 64m+64)
    // (sc1 atomic loads bypass caches — no fence needed)
    const __hip_bfloat16* hf = h0;           // t=511 (odd) wrote h0
    int wig = n * 4 + w;                     // wave index in group, 0..255
    for (int p = wig; p < 64 * C_; p += 256) {
        int row = m * 64 + p / C_;
        int cc  = p % C_;
        const u64* hr = (const u64*)(hf + row * H_);
        const float* wr = wph + cc * H_;
        float acc = 0.f;
#pragma unroll
        for (int j = 0; j < 4; ++j) {
            int k = j * 256 + l * 4;
            u64 hv4 = __hip_atomic_load(hr + (k >> 2), __ATOMIC_RELAXED, __HIP_MEMORY_SCOPE_AGENT);
            union { u64 q; unsigned short s[4]; } u_; u_.q = hv4;
            float4 wv = *(const float4*)(wr + k);
            acc += bf2f(u_.s[0]) * wv.x + bf2f(u_.s[1]) * wv.y
                 + bf2f(u_.s[2]) * wv.z + bf2f(u_.s[3]) * wv.w;
        }
#pragma unroll
        for (int off = 32; off > 0; off >>= 1) acc += __shfl_down(acc, off, 64);
        if (l == 0) out[row * C_ + cc] = acc + bp[cc];
    }
}

extern "C" void kernel_launch(void* const* d_in, const int* in_sizes, int n_in,
                              void* d_out, int out_size, void* d_ws, size_t ws_size,
                              hipStream_t stream) {
    const float* x   = (const float*)d_in[0];
    const float* wgx = (const float*)d_in[1];
    const float* wix = (const float*)d_in[2];
    const float* wfx = (const float*)d_in[3];
    const float* wox = (const float*)d_in[4];
    const float* wgh = (const float*)d_in[5];
    const float* wih = (const float*)d_in[6];
    const float* wfh = (const float*)d_in[7];
    const float* woh = (const float*)d_in[8];
    const float* wph = (const float*)d_in[9];
    const float* bg  = (const float*)d_in[10];
    const float* bi  = (const float*)d_in[11];
    const float* bf  = (const float*)d_in[12];
    const float* bo  = (const float*)d_in[13];
    const float* bp  = (const float*)d_in[14];
    float* out = (float*)d_out;

    char* ws = (char*)d_ws;
    unsigned*       flags = (unsigned*)ws;
    float*          xT = (float*)(ws + 4096);
    __hip_bfloat16* h0 = (__hip_bfloat16*)(ws + 4096 + 524288);
    __hip_bfloat16* h1 = (__hip_bfloat16*)(ws + 4096 + 2 * 524288);
    __hip_bfloat16* Wp = (__hip_bfloat16*)(ws + 4096 + 3 * 524288);

    hipMemsetAsync(flags, 0, 4096, stream);               // flag barrier = 0
    hipMemsetAsync(h0, 0, 524288, stream);                // h_0 = 0
    prep_x<<<512, 256, 0, stream>>>(x, xT);
    prep_w<<<2048, 256, 0, stream>>>(wgh, wih, wfh, woh, Wp);
    lstm_main<<<256, 256, 0, stream>>>(xT, wgx, wix, wfx, wox, bg, bi, bf, bo,
                                       Wp, h0, h1, wph, bp, out, flags);
}